// Round 2
// baseline (6472.616 us; speedup 1.0000x reference)
//
#include <hip/hip_runtime.h>
#include <math.h>

#define HID 2048
#define VOC 28
#define TLEN 512
#define NBLK 256
#define NTHR 512

#define ATOM_ST64(p, v) __hip_atomic_store((unsigned long long*)(p), (v), __ATOMIC_RELAXED, __HIP_MEMORY_SCOPE_AGENT)
#define ATOM_LD64(p)    __hip_atomic_load((const unsigned long long*)(p), __ATOMIC_RELAXED, __HIP_MEMORY_SCOPE_AGENT)
#define ATOM_ST32(p, v) __hip_atomic_store((p), (v), __ATOMIC_RELAXED, __HIP_MEMORY_SCOPE_AGENT)
#define ATOM_LD32(p)    __hip_atomic_load((p), __ATOMIC_RELAXED, __HIP_MEMORY_SCOPE_AGENT)

// ---------------------------------------------------------------------------
// K1: xp[v][row] = sum_k emb[v][k] * Wih[row][k] + bih[row] + bhh[row]
// ---------------------------------------------------------------------------
__global__ __launch_bounds__(256) void k_xproj(
    const float* __restrict__ emb, const float* __restrict__ Wih,
    const float* __restrict__ bih, const float* __restrict__ bhh,
    float* __restrict__ xp)
{
  const int slab = blockIdx.x;      // rows [slab*32, slab*32+32)
  const int t = threadIdx.x;
  const int v = t & 31;             // vocab lane (>=28 inactive)
  const int sub = t >> 5;           // 8 column groups of 32 (per 256-chunk)
  const int w = t >> 6;             // wave id (4)
  __shared__ float embl[VOC][257];  // +1 pad: conflict-free row access
  __shared__ float red[4][32][33];  // +1 pad
  float acc[32];
#pragma unroll
  for (int r = 0; r < 32; ++r) acc[r] = 0.f;
  const int vv = (v < VOC) ? v : 0;
  for (int c = 0; c < 8; ++c) {
    __syncthreads();
    for (int e = t; e < VOC * 256; e += 256) {
      int ev = e >> 8, ek = e & 255;
      embl[ev][ek] = emb[ev * HID + c * 256 + ek];
    }
    __syncthreads();
    float el[32];
#pragma unroll
    for (int i = 0; i < 32; ++i) el[i] = embl[vv][sub * 32 + i];
    for (int r = 0; r < 32; ++r) {
      const float4* wr = (const float4*)(Wih + (size_t)(slab * 32 + r) * HID + c * 256 + sub * 32);
      float a = acc[r];
#pragma unroll
      for (int q = 0; q < 8; ++q) {
        float4 wv = wr[q];
        a = fmaf(el[q * 4 + 0], wv.x, a);
        a = fmaf(el[q * 4 + 1], wv.y, a);
        a = fmaf(el[q * 4 + 2], wv.z, a);
        a = fmaf(el[q * 4 + 3], wv.w, a);
      }
      acc[r] = a;
    }
  }
#pragma unroll
  for (int r = 0; r < 32; ++r) acc[r] += __shfl_xor(acc[r], 32);
  if ((t & 32) == 0) {
#pragma unroll
    for (int r = 0; r < 32; ++r) red[w][v][r] = acc[r];
  }
  __syncthreads();
  for (int p = t; p < VOC * 32; p += 256) {
    int pv = p >> 5, pr = p & 31;
    float s = red[0][pv][pr] + red[1][pv][pr] + red[2][pv][pr] + red[3][pv][pr];
    int row = slab * 32 + pr;
    xp[(size_t)pv * (4 * HID) + row] = s + bih[row] + bhh[row];
  }
}

// ---------------------------------------------------------------------------
// Persistent cooperative LSTM kernel — barrier-free tagged dataflow with a
// cheap "hint tag" layer to kill LLC poll-traffic amplification.
//
// Layer 1 (hint): per-producer u32 tag, 256 words = 1 KB per slot. Stored
//   RELAXED right after the data words (no vmcnt ordering!). Consumers spin
//   here: rounds cost 1 KB/block instead of 16 KB/block (16x fewer LLC
//   bank-visits on the shared lines).
// Layer 2 (truth): each h element is an 8-byte word (epoch<<32 | f32 bits).
//   Read ONCE after the hint matches; the embedded epoch tags verify real
//   visibility. If the hint store raced ahead of a data word, the embedded
//   spin catches it — the hint is a pure traffic optimization, never a
//   correctness dependency.
//
// Slot rotation (slot = epoch & 1) is race-free by the same induction as
// before: a producer publishes e+2 (overwriting e) only after consuming e+1,
// which requires every block to have published e+1, which requires every
// block to have consumed e. Tags are monotone; launch-time memset clears
// stale tags (tag 0 never matches an expected >= 1).
// ---------------------------------------------------------------------------
struct MainArgs {
  const float* enc_Whh;
  const float* dec_Whh;
  const int* x;
  const int* target;
  const float* eps;
  const float* mu_W; const float* mu_b;
  const float* lv_W; const float* lv_b;
  const float* xp_enc; const float* xp_dec;
  unsigned long long* tag0;       // slot 0: HID tagged words (16 KB)
  unsigned long long* tag1;       // slot 1: HID tagged words (16 KB)
  unsigned* ctag0;                // slot 0: NBLK hint tags (1 KB)
  unsigned* ctag1;                // slot 1: NBLK hint tags (1 KB)
  float* out_res; float* out_dec; float* out_mu; float* out_lv;
};

__device__ __forceinline__ unsigned long long pack_he(float h, unsigned e) {
  return ((unsigned long long)e << 32) | (unsigned long long)__float_as_uint(h);
}

// Spin on the hint tags: thread t (<NBLK) waits for producer t's hint.
__device__ __forceinline__ void hint_wait(const unsigned* __restrict__ ct,
                                          unsigned epoch, int t) {
  if (t < NBLK) {
    while (ATOM_LD32(ct + t) < epoch) { }
  }
  __atomic_signal_fence(__ATOMIC_ACQUIRE);
  __syncthreads();
}

// Gather the full h vector for `epoch` into h_lds (4 elems per thread).
// Hint already matched, so the embedded-tag loop almost always passes on
// the first try; it only spins on a hint/data visibility race.
__device__ __forceinline__ void gather_h(const unsigned long long* __restrict__ src,
                                         unsigned epoch, float* h_lds, int t) {
  unsigned long long w0 = ATOM_LD64(src + t);
  unsigned long long w1 = ATOM_LD64(src + t + 512);
  unsigned long long w2 = ATOM_LD64(src + t + 1024);
  unsigned long long w3 = ATOM_LD64(src + t + 1536);
  while ((unsigned)(w0 >> 32) != epoch || (unsigned)(w1 >> 32) != epoch ||
         (unsigned)(w2 >> 32) != epoch || (unsigned)(w3 >> 32) != epoch) {
    if ((unsigned)(w0 >> 32) != epoch) w0 = ATOM_LD64(src + t);
    if ((unsigned)(w1 >> 32) != epoch) w1 = ATOM_LD64(src + t + 512);
    if ((unsigned)(w2 >> 32) != epoch) w2 = ATOM_LD64(src + t + 1024);
    if ((unsigned)(w3 >> 32) != epoch) w3 = ATOM_LD64(src + t + 1536);
  }
  h_lds[t]        = __uint_as_float((unsigned)w0);
  h_lds[t + 512]  = __uint_as_float((unsigned)w1);
  h_lds[t + 1024] = __uint_as_float((unsigned)w2);
  h_lds[t + 1536] = __uint_as_float((unsigned)w3);
}

__global__ __launch_bounds__(NTHR) void k_main(MainArgs a) {
  const int b = blockIdx.x;
  const int t = threadIdx.x;
  const int base_j = b * 8;
  const int r = t >> 4;           // 0..31 : gate*8 + jj
  const int cs = t & 15;
  const int gate = r >> 3;
  const int jj = r & 7;
  const size_t row_g = (size_t)gate * HID + base_j + jj;

  __shared__ float h_lds[HID];
  __shared__ float gsum[32];
  __shared__ float xparr[32];
  __shared__ int toks[2 * TLEN];

  toks[t] = a.x[t];
  toks[TLEN + t] = (t == 0) ? 0 : a.target[t - 1];
  float c_reg = 0.f;                                 // c0 = 0 (held by t<8)

  float4 w4[32];
  {
    const float* wp = a.enc_Whh + row_g * HID + cs * 4;
#pragma unroll
    for (int m = 0; m < 32; ++m) w4[m] = *(const float4*)(wp + m * 64);
  }
  unsigned long long* tb[2] = {a.tag0, a.tag1};
  unsigned* cb[2] = {a.ctag0, a.ctag1};
  unsigned epoch = 1;                                // h0 carries tag 1
  if (t < 8) ATOM_ST64(&tb[1][base_j + t], pack_he(0.f, 1u));  // slot = 1&1
  if (t == 0) ATOM_ST32(&cb[1][b], 1u);
  __syncthreads();                                   // toks ready

  for (int phase = 0; phase < 2; ++phase) {
    const float* xp = phase ? a.xp_dec : a.xp_enc;
    const int* tk = &toks[phase * TLEN];
    for (int s = 0; s < TLEN; ++s) {
      // xp load first: its latency hides under the hint spin
      float xpv = 0.f;
      if (t < 32) xpv = xp[(size_t)tk[s] * (4 * HID) + (t >> 3) * HID + base_j + (t & 7)];
      hint_wait(cb[epoch & 1], epoch, t);
      gather_h(tb[epoch & 1], epoch, h_lds, t);
      if (t < 32) xparr[t] = xpv;
      __syncthreads();
      float acc = 0.f;
      const float4* h4 = (const float4*)h_lds;
#pragma unroll
      for (int m = 0; m < 32; ++m) {
        float4 hh = h4[(m << 4) + cs];
        float4 ww = w4[m];
        acc = fmaf(ww.x, hh.x, acc);
        acc = fmaf(ww.y, hh.y, acc);
        acc = fmaf(ww.z, hh.z, acc);
        acc = fmaf(ww.w, hh.w, acc);
      }
      acc += __shfl_xor(acc, 1);
      acc += __shfl_xor(acc, 2);
      acc += __shfl_xor(acc, 4);
      acc += __shfl_xor(acc, 8);
      if (cs == 0) gsum[r] = acc;
      __syncthreads();
      // parallel activations: lanes 0-31 of wave 0 (i,f,g,o blocks of 8)
      if (t < 32) {
        float g = gsum[t] + xparr[t];
        bool is_g = (t >= 16) && (t < 24);
        float act = is_g ? tanhf(g) : (1.f / (1.f + expf(-g)));
        float sf = __shfl(act, (t & 7) + 8);
        float tg = __shfl(act, (t & 7) + 16);
        float so = __shfl(act, (t & 7) + 24);
        if (t < 8) {
          float si = act;
          c_reg = sf * c_reg + si * tg;
          float hn = so * tanhf(c_reg);
          ATOM_ST64(&tb[(epoch + 1) & 1][base_j + t], pack_he(hn, epoch + 1));
          if (phase) a.out_dec[(size_t)s * HID + base_j + t] = hn;
        }
        // hint AFTER the data store issues (same lane program order; HW may
        // still reorder visibility — the embedded tags catch that case)
        if (t == 0) ATOM_ST32(&cb[(epoch + 1) & 1][b], epoch + 1);
      }
      ++epoch;
      // No barrier here: h_lds overwrite next step is safe (matvec reads
      // completed at the post-matvec __syncthreads; activations only read
      // gsum/xparr). Non-publishing waves go straight to the hint spin.
    }
    if (phase == 0) {
      // ---- mu / logvar / z (h_enc carries tag `epoch`) ----
      hint_wait(cb[epoch & 1], epoch, t);
      gather_h(tb[epoch & 1], epoch, h_lds, t);
      __syncthreads();
      const int r16 = t >> 5, cs32 = t & 31;    // 16 rows x 32 lanes
      const int mrow = base_j + (r16 & 7);
      const float* Wrow = (r16 < 8 ? a.mu_W : a.lv_W) + (size_t)mrow * HID + cs32 * 4;
      float acc = 0.f;
      const float4* h4 = (const float4*)h_lds;
#pragma unroll
      for (int m = 0; m < 16; ++m) {
        float4 wv = *(const float4*)(Wrow + m * 128);
        float4 hh = h4[(m << 5) + cs32];
        acc = fmaf(wv.x, hh.x, acc);
        acc = fmaf(wv.y, hh.y, acc);
        acc = fmaf(wv.z, hh.z, acc);
        acc = fmaf(wv.w, hh.w, acc);
      }
      acc += __shfl_xor(acc, 1);
      acc += __shfl_xor(acc, 2);
      acc += __shfl_xor(acc, 4);
      acc += __shfl_xor(acc, 8);
      acc += __shfl_xor(acc, 16);
      if (cs32 == 0) gsum[r16] = acc + (r16 < 8 ? a.mu_b[mrow] : a.lv_b[mrow]);
      __syncthreads();
      if (t < 8) {
        float mu = gsum[t], lv = gsum[8 + t];
        a.out_mu[base_j + t] = mu;
        a.out_lv[base_j + t] = lv;
        float z = fmaf(a.eps[base_j + t], expf(0.5f * lv), mu);
        ATOM_ST64(&tb[(epoch + 1) & 1][base_j + t], pack_he(z, epoch + 1));
      }
      if (t == 0) ATOM_ST32(&cb[(epoch + 1) & 1][b], epoch + 1);
      // reload weights for decoder (private; overlaps others' spin)
      {
        const float* wp = a.dec_Whh + row_g * HID + cs * 4;
#pragma unroll
        for (int m = 0; m < 32; ++m) w4[m] = *(const float4*)(wp + m * 64);
      }
      ++epoch;   // decoder gathers z at this tag
    }
  }
}

// ---------------------------------------------------------------------------
// Argmax over each dec_outs row (first-index tie semantics, like jnp.argmax)
// ---------------------------------------------------------------------------
__global__ __launch_bounds__(256) void k_argmax(const float* __restrict__ dec,
                                               float* __restrict__ res) {
  const int row = blockIdx.x;
  const int t = threadIdx.x;
  const float4* d4 = (const float4*)(dec + (size_t)row * HID);
  float bv = -INFINITY; int bi = 0;
#pragma unroll
  for (int k = 0; k < 2; ++k) {
    int p = t + k * 256;
    float4 v = d4[p];
    int i0 = p * 4;
    if (v.x > bv) { bv = v.x; bi = i0; }
    if (v.y > bv) { bv = v.y; bi = i0 + 1; }
    if (v.z > bv) { bv = v.z; bi = i0 + 2; }
    if (v.w > bv) { bv = v.w; bi = i0 + 3; }
  }
  for (int off = 1; off < 64; off <<= 1) {
    float ov = __shfl_xor(bv, off);
    int oi = __shfl_xor(bi, off);
    if (ov > bv || (ov == bv && oi < bi)) { bv = ov; bi = oi; }
  }
  __shared__ float sv[4];
  __shared__ int si[4];
  if ((t & 63) == 0) { sv[t >> 6] = bv; si[t >> 6] = bi; }
  __syncthreads();
  if (t == 0) {
    for (int ww = 1; ww < 4; ++ww)
      if (sv[ww] > bv || (sv[ww] == bv && si[ww] < bi)) { bv = sv[ww]; bi = si[ww]; }
    res[row] = (float)bi;
  }
}

// ---------------------------------------------------------------------------
extern "C" void kernel_launch(void* const* d_in, const int* in_sizes, int n_in,
                              void* d_out, int out_size, void* d_ws, size_t ws_size,
                              hipStream_t stream) {
  (void)in_sizes; (void)n_in; (void)out_size; (void)ws_size;
  const int* x        = (const int*)d_in[0];
  const int* target   = (const int*)d_in[1];
  const float* eps    = (const float*)d_in[2];
  const float* enc_emb = (const float*)d_in[3];
  const float* enc_Wih = (const float*)d_in[4];
  const float* enc_Whh = (const float*)d_in[5];
  const float* enc_bih = (const float*)d_in[6];
  const float* enc_bhh = (const float*)d_in[7];
  const float* mu_W   = (const float*)d_in[8];
  const float* mu_b   = (const float*)d_in[9];
  const float* lv_W   = (const float*)d_in[10];
  const float* lv_b   = (const float*)d_in[11];
  const float* dec_emb = (const float*)d_in[12];
  const float* dec_Wih = (const float*)d_in[13];
  const float* dec_Whh = (const float*)d_in[14];
  const float* dec_bih = (const float*)d_in[15];
  const float* dec_bhh = (const float*)d_in[16];

  float* out = (float*)d_out;
  char* ws = (char*)d_ws;
  unsigned* ctag0 = (unsigned*)ws;                               // 1 KB
  unsigned* ctag1 = (unsigned*)(ws + 2048);                      // 1 KB
  unsigned long long* tag0 = (unsigned long long*)(ws + 4096);   // 16 KB
  unsigned long long* tag1 = tag0 + HID;                          // 16 KB
  float* xp_enc = (float*)(tag1 + HID);                           // 28*8192 f32
  float* xp_dec = xp_enc + VOC * 4 * HID;

  // Clear hint + data tags (tag 0 never matches an expected epoch >= 1)
  hipMemsetAsync(ws, 0, 4096 + 2 * HID * sizeof(unsigned long long), stream);
  k_xproj<<<NBLK, 256, 0, stream>>>(enc_emb, enc_Wih, enc_bih, enc_bhh, xp_enc);
  k_xproj<<<NBLK, 256, 0, stream>>>(dec_emb, dec_Wih, dec_bih, dec_bhh, xp_dec);

  MainArgs a;
  a.enc_Whh = enc_Whh; a.dec_Whh = dec_Whh;
  a.x = x; a.target = target; a.eps = eps;
  a.mu_W = mu_W; a.mu_b = mu_b; a.lv_W = lv_W; a.lv_b = lv_b;
  a.xp_enc = xp_enc; a.xp_dec = xp_dec;
  a.tag0 = tag0; a.tag1 = tag1;
  a.ctag0 = ctag0; a.ctag1 = ctag1;
  a.out_res = out;
  a.out_dec = out + TLEN;
  a.out_mu  = out + TLEN + (size_t)TLEN * HID;
  a.out_lv  = out + TLEN + (size_t)TLEN * HID + HID;

  void* kargs[] = {(void*)&a};
  hipLaunchCooperativeKernel((void*)k_main, dim3(NBLK), dim3(NTHR), kargs, 0, stream);

  k_argmax<<<TLEN, 256, 0, stream>>>(out + TLEN, out);
}

// Round 3
// 3272.980 us; speedup vs baseline: 1.9776x; 1.9776x over previous
//
#include <hip/hip_runtime.h>
#include <math.h>

#define HID 2048
#define VOC 28
#define TLEN 512
#define NBLK 256
#define NTHR 512

#define ATOM_ST64(p, v) __hip_atomic_store((unsigned long long*)(p), (v), __ATOMIC_RELAXED, __HIP_MEMORY_SCOPE_AGENT)
#define ATOM_LD64(p)    __hip_atomic_load((const unsigned long long*)(p), __ATOMIC_RELAXED, __HIP_MEMORY_SCOPE_AGENT)

// ---------------------------------------------------------------------------
// K1: xp[v][row] = sum_k emb[v][k] * Wih[row][k] + bih[row] + bhh[row]
// ---------------------------------------------------------------------------
__global__ __launch_bounds__(256) void k_xproj(
    const float* __restrict__ emb, const float* __restrict__ Wih,
    const float* __restrict__ bih, const float* __restrict__ bhh,
    float* __restrict__ xp)
{
  const int slab = blockIdx.x;      // rows [slab*32, slab*32+32)
  const int t = threadIdx.x;
  const int v = t & 31;             // vocab lane (>=28 inactive)
  const int sub = t >> 5;           // 8 column groups of 32 (per 256-chunk)
  const int w = t >> 6;             // wave id (4)
  __shared__ float embl[VOC][257];  // +1 pad: conflict-free row access
  __shared__ float red[4][32][33];  // +1 pad
  float acc[32];
#pragma unroll
  for (int r = 0; r < 32; ++r) acc[r] = 0.f;
  const int vv = (v < VOC) ? v : 0;
  for (int c = 0; c < 8; ++c) {
    __syncthreads();
    for (int e = t; e < VOC * 256; e += 256) {
      int ev = e >> 8, ek = e & 255;
      embl[ev][ek] = emb[ev * HID + c * 256 + ek];
    }
    __syncthreads();
    float el[32];
#pragma unroll
    for (int i = 0; i < 32; ++i) el[i] = embl[vv][sub * 32 + i];
    for (int r = 0; r < 32; ++r) {
      const float4* wr = (const float4*)(Wih + (size_t)(slab * 32 + r) * HID + c * 256 + sub * 32);
      float a = acc[r];
#pragma unroll
      for (int q = 0; q < 8; ++q) {
        float4 wv = wr[q];
        a = fmaf(el[q * 4 + 0], wv.x, a);
        a = fmaf(el[q * 4 + 1], wv.y, a);
        a = fmaf(el[q * 4 + 2], wv.z, a);
        a = fmaf(el[q * 4 + 3], wv.w, a);
      }
      acc[r] = a;
    }
  }
#pragma unroll
  for (int r = 0; r < 32; ++r) acc[r] += __shfl_xor(acc[r], 32);
  if ((t & 32) == 0) {
#pragma unroll
    for (int r = 0; r < 32; ++r) red[w][v][r] = acc[r];
  }
  __syncthreads();
  for (int p = t; p < VOC * 32; p += 256) {
    int pv = p >> 5, pr = p & 31;
    float s = red[0][pv][pr] + red[1][pv][pr] + red[2][pv][pr] + red[3][pv][pr];
    int row = slab * 32 + pr;
    xp[(size_t)pv * (4 * HID) + row] = s + bih[row] + bhh[row];
  }
}

// ---------------------------------------------------------------------------
// Persistent cooperative LSTM — R1's barrier-free tagged dataflow (payload
// travels WITH discovery; polling spread over 256 lines, one poller per word
// per block) + 4-gate-fused matvec.
//
// Communication (unchanged from the verified R1 scheme): each h element is
// one 8-byte relaxed agent-scope word (epoch<<32 | f32 bits); consumers spin
// on the element words until tag == expected epoch. 2-slot parity rotation
// (slot = epoch&1) is race-free by induction: a producer overwrites epoch e
// only after consuming e+1, which requires all blocks to have published e+1,
// which requires all blocks to have consumed e.
//
// Matvec (new): thread t = ck*8 + jj handles column chunk ck (32 floats) for
// ALL FOUR gate rows of output jj — each h float4 is read once per thread
// instead of once per (gate,thread): 64 ds_read_b128/block/step vs 256.
// h is staged in a padded layout hpad[ck][9 float4] (bank = 4ck+4q mod 32:
// the 8 chunk-lanes of a wave hit 8 disjoint 4-bank groups; the 8 jj lanes
// broadcast). Cross-wave reduction via wred[4][8][8] + one barrier.
// ---------------------------------------------------------------------------
struct MainArgs {
  const float* enc_Whh;
  const float* dec_Whh;
  const int* x;
  const int* target;
  const float* eps;
  const float* mu_W; const float* mu_b;
  const float* lv_W; const float* lv_b;
  const float* xp_enc; const float* xp_dec;
  unsigned long long* tag0;       // slot 0: HID tagged words (16 KB)
  unsigned long long* tag1;       // slot 1: HID tagged words (16 KB)
  float* out_res; float* out_dec; float* out_mu; float* out_lv;
};

__device__ __forceinline__ unsigned long long pack_he(float h, unsigned e) {
  return ((unsigned long long)e << 32) | (unsigned long long)__float_as_uint(h);
}

// linear h index -> padded float index: hpad[ck][q][e] with 9-float4 rows
__device__ __forceinline__ int hp_idx(int i) {
  return ((i >> 5) * 36) + (((i >> 2) & 7) << 2) + (i & 3);
}

// Spin-gather the full h vector for `epoch` into hpad (4 elems per thread).
// Payload-carrying poll: the load that discovers the tag IS the data load.
// s_sleep(1) backoff in the retry path only (first attempt immediate).
__device__ __forceinline__ void gather_h(const unsigned long long* __restrict__ src,
                                         unsigned epoch, float* hpad, int t) {
  unsigned long long w0 = ATOM_LD64(src + t);
  unsigned long long w1 = ATOM_LD64(src + t + 512);
  unsigned long long w2 = ATOM_LD64(src + t + 1024);
  unsigned long long w3 = ATOM_LD64(src + t + 1536);
  while ((unsigned)(w0 >> 32) != epoch || (unsigned)(w1 >> 32) != epoch ||
         (unsigned)(w2 >> 32) != epoch || (unsigned)(w3 >> 32) != epoch) {
    __builtin_amdgcn_s_sleep(1);
    if ((unsigned)(w0 >> 32) != epoch) w0 = ATOM_LD64(src + t);
    if ((unsigned)(w1 >> 32) != epoch) w1 = ATOM_LD64(src + t + 512);
    if ((unsigned)(w2 >> 32) != epoch) w2 = ATOM_LD64(src + t + 1024);
    if ((unsigned)(w3 >> 32) != epoch) w3 = ATOM_LD64(src + t + 1536);
  }
  hpad[hp_idx(t)]        = __uint_as_float((unsigned)w0);
  hpad[hp_idx(t + 512)]  = __uint_as_float((unsigned)w1);
  hpad[hp_idx(t + 1024)] = __uint_as_float((unsigned)w2);
  hpad[hp_idx(t + 1536)] = __uint_as_float((unsigned)w3);
}

__global__ __launch_bounds__(NTHR) void k_main(MainArgs a) {
  const int b = blockIdx.x;
  const int t = threadIdx.x;
  const int base_j = b * 8;
  const int jj = t & 7;           // output element within the block's 8
  const int ck = t >> 3;          // 0..63 column chunk of 32 floats

  __shared__ __align__(16) float hpad[64 * 36];  // padded h (9216 B)
  __shared__ float wred[4 * 8 * 8];              // [gate][jj][wave]
  __shared__ float gsum[32];
  __shared__ int toks[2 * TLEN];

  toks[t] = a.x[t];
  toks[TLEN + t] = (t == 0) ? 0 : a.target[t - 1];
  float c_reg = 0.f;                              // c0 = 0 (held by t<8)

  // weights: w4[g*8+q] = Whh row (g*HID + base_j + jj), cols ck*32+q*4 ..+3
  float4 w4[32];
#pragma unroll
  for (int g = 0; g < 4; ++g) {
    const float* wp = a.enc_Whh + ((size_t)(g * HID + base_j + jj)) * HID + ck * 32;
#pragma unroll
    for (int q = 0; q < 8; ++q) w4[g * 8 + q] = *(const float4*)(wp + q * 4);
  }

  unsigned long long* tb[2] = {a.tag0, a.tag1};
  unsigned epoch = 1;                             // h0 carries tag 1
  if (t < 8) ATOM_ST64(&tb[1][base_j + t], pack_he(0.f, 1u));  // slot = 1&1
  __syncthreads();                                // toks ready

  for (int phase = 0; phase < 2; ++phase) {
    const float* xp = phase ? a.xp_dec : a.xp_enc;
    const int* tk = &toks[phase * TLEN];
    for (int s = 0; s < TLEN; ++s) {
      // xp load first: latency hides under the gather spin; stays in the
      // register of the thread that consumes it (t<32 -> gate t>>3, jj t&7)
      float xpv = 0.f;
      if (t < 32) xpv = xp[(size_t)tk[s] * (4 * HID) + (t >> 3) * HID + base_j + (t & 7)];
      gather_h(tb[epoch & 1], epoch, hpad, t);
      __syncthreads();
      // 4-gate fused matvec: 8 ds_read_b128 + 128 FMA per thread
      float p0 = 0.f, p1 = 0.f, p2 = 0.f, p3 = 0.f;
      const float4* h4 = (const float4*)hpad;
#pragma unroll
      for (int q = 0; q < 8; ++q) {
        float4 hh = h4[ck * 9 + q];
        float4 wa = w4[q], wb = w4[8 + q], wc = w4[16 + q], wd = w4[24 + q];
        p0 = fmaf(wa.x, hh.x, p0); p0 = fmaf(wa.y, hh.y, p0);
        p0 = fmaf(wa.z, hh.z, p0); p0 = fmaf(wa.w, hh.w, p0);
        p1 = fmaf(wb.x, hh.x, p1); p1 = fmaf(wb.y, hh.y, p1);
        p1 = fmaf(wb.z, hh.z, p1); p1 = fmaf(wb.w, hh.w, p1);
        p2 = fmaf(wc.x, hh.x, p2); p2 = fmaf(wc.y, hh.y, p2);
        p2 = fmaf(wc.z, hh.z, p2); p2 = fmaf(wc.w, hh.w, p2);
        p3 = fmaf(wd.x, hh.x, p3); p3 = fmaf(wd.y, hh.y, p3);
        p3 = fmaf(wd.z, hh.z, p3); p3 = fmaf(wd.w, hh.w, p3);
      }
      // in-wave reduce across the 8 chunk-lanes (bits 3..5 of lane id)
      p0 += __shfl_xor(p0, 8);  p0 += __shfl_xor(p0, 16); p0 += __shfl_xor(p0, 32);
      p1 += __shfl_xor(p1, 8);  p1 += __shfl_xor(p1, 16); p1 += __shfl_xor(p1, 32);
      p2 += __shfl_xor(p2, 8);  p2 += __shfl_xor(p2, 16); p2 += __shfl_xor(p2, 32);
      p3 += __shfl_xor(p3, 8);  p3 += __shfl_xor(p3, 16); p3 += __shfl_xor(p3, 32);
      if ((t & 56) == 0) {                       // one lane per (wave, jj)
        int wv = t >> 6;
        wred[jj * 8 + wv]       = p0;
        wred[64 + jj * 8 + wv]  = p1;
        wred[128 + jj * 8 + wv] = p2;
        wred[192 + jj * 8 + wv] = p3;
      }
      __syncthreads();
      // final reduce + activations in wave 0 (t<32: gate t>>3, jj t&7)
      if (t < 32) {
        const float* wr = wred + (t >> 3) * 64 + (t & 7) * 8;
        float accv = 0.f;
#pragma unroll
        for (int w = 0; w < 8; ++w) accv += wr[w];
        float g = accv + xpv;
        bool is_g = (t >= 16) && (t < 24);
        float act = is_g ? tanhf(g) : (1.f / (1.f + expf(-g)));
        float sf = __shfl(act, (t & 7) + 8);
        float tg = __shfl(act, (t & 7) + 16);
        float so = __shfl(act, (t & 7) + 24);
        if (t < 8) {
          float si = act;
          c_reg = sf * c_reg + si * tg;
          float hn = so * tanhf(c_reg);
          ATOM_ST64(&tb[(epoch + 1) & 1][base_j + t], pack_he(hn, epoch + 1));
          if (phase) a.out_dec[(size_t)s * HID + base_j + t] = hn;
        }
      }
      ++epoch;
      // No barrier: next gather's hpad writes are safe (all matvec reads of
      // hpad completed at the post-wred __syncthreads; the t<32 tail reads
      // only wred, which next step writes only after its post-gather sync).
    }
    if (phase == 0) {
      // ---- mu / logvar / z (h_enc carries tag `epoch`) ----
      gather_h(tb[epoch & 1], epoch, hpad, t);
      __syncthreads();
      const int r16 = t >> 5, cs32 = t & 31;    // 16 rows x 32 lanes
      const int mrow = base_j + (r16 & 7);
      const float* Wrow = (r16 < 8 ? a.mu_W : a.lv_W) + (size_t)mrow * HID + cs32 * 4;
      float acc = 0.f;
      const float4* h4 = (const float4*)hpad;
#pragma unroll
      for (int m = 0; m < 16; ++m) {
        float4 wv = *(const float4*)(Wrow + m * 128);
        int f = m * 32 + cs32;                   // float4 index in h
        float4 hh = h4[((f >> 3) * 9) + (f & 7)];
        acc = fmaf(wv.x, hh.x, acc);
        acc = fmaf(wv.y, hh.y, acc);
        acc = fmaf(wv.z, hh.z, acc);
        acc = fmaf(wv.w, hh.w, acc);
      }
      acc += __shfl_xor(acc, 1);
      acc += __shfl_xor(acc, 2);
      acc += __shfl_xor(acc, 4);
      acc += __shfl_xor(acc, 8);
      acc += __shfl_xor(acc, 16);
      if (cs32 == 0) gsum[r16] = acc + (r16 < 8 ? a.mu_b[mrow] : a.lv_b[mrow]);
      __syncthreads();
      if (t < 8) {
        float mu = gsum[t], lv = gsum[8 + t];
        a.out_mu[base_j + t] = mu;
        a.out_lv[base_j + t] = lv;
        float z = fmaf(a.eps[base_j + t], expf(0.5f * lv), mu);
        ATOM_ST64(&tb[(epoch + 1) & 1][base_j + t], pack_he(z, epoch + 1));
      }
      // reload weights for decoder (private; overlaps others' spin)
#pragma unroll
      for (int g = 0; g < 4; ++g) {
        const float* wp = a.dec_Whh + ((size_t)(g * HID + base_j + jj)) * HID + ck * 32;
#pragma unroll
        for (int q = 0; q < 8; ++q) w4[g * 8 + q] = *(const float4*)(wp + q * 4);
      }
      ++epoch;   // decoder gathers z at this tag
    }
  }
}

// ---------------------------------------------------------------------------
// Argmax over each dec_outs row (first-index tie semantics, like jnp.argmax)
// ---------------------------------------------------------------------------
__global__ __launch_bounds__(256) void k_argmax(const float* __restrict__ dec,
                                               float* __restrict__ res) {
  const int row = blockIdx.x;
  const int t = threadIdx.x;
  const float4* d4 = (const float4*)(dec + (size_t)row * HID);
  float bv = -INFINITY; int bi = 0;
#pragma unroll
  for (int k = 0; k < 2; ++k) {
    int p = t + k * 256;
    float4 v = d4[p];
    int i0 = p * 4;
    if (v.x > bv) { bv = v.x; bi = i0; }
    if (v.y > bv) { bv = v.y; bi = i0 + 1; }
    if (v.z > bv) { bv = v.z; bi = i0 + 2; }
    if (v.w > bv) { bv = v.w; bi = i0 + 3; }
  }
  for (int off = 1; off < 64; off <<= 1) {
    float ov = __shfl_xor(bv, off);
    int oi = __shfl_xor(bi, off);
    if (ov > bv || (ov == bv && oi < bi)) { bv = ov; bi = oi; }
  }
  __shared__ float sv[4];
  __shared__ int si[4];
  if ((t & 63) == 0) { sv[t >> 6] = bv; si[t >> 6] = bi; }
  __syncthreads();
  if (t == 0) {
    for (int ww = 1; ww < 4; ++ww)
      if (sv[ww] > bv || (sv[ww] == bv && si[ww] < bi)) { bv = sv[ww]; bi = si[ww]; }
    res[row] = (float)bi;
  }
}

// ---------------------------------------------------------------------------
extern "C" void kernel_launch(void* const* d_in, const int* in_sizes, int n_in,
                              void* d_out, int out_size, void* d_ws, size_t ws_size,
                              hipStream_t stream) {
  (void)in_sizes; (void)n_in; (void)out_size; (void)ws_size;
  const int* x        = (const int*)d_in[0];
  const int* target   = (const int*)d_in[1];
  const float* eps    = (const float*)d_in[2];
  const float* enc_emb = (const float*)d_in[3];
  const float* enc_Wih = (const float*)d_in[4];
  const float* enc_Whh = (const float*)d_in[5];
  const float* enc_bih = (const float*)d_in[6];
  const float* enc_bhh = (const float*)d_in[7];
  const float* mu_W   = (const float*)d_in[8];
  const float* mu_b   = (const float*)d_in[9];
  const float* lv_W   = (const float*)d_in[10];
  const float* lv_b   = (const float*)d_in[11];
  const float* dec_emb = (const float*)d_in[12];
  const float* dec_Wih = (const float*)d_in[13];
  const float* dec_Whh = (const float*)d_in[14];
  const float* dec_bih = (const float*)d_in[15];
  const float* dec_bhh = (const float*)d_in[16];

  float* out = (float*)d_out;
  char* ws = (char*)d_ws;
  unsigned long long* tag0 = (unsigned long long*)(ws + 4096);   // 16 KB
  unsigned long long* tag1 = tag0 + HID;                          // 16 KB
  float* xp_enc = (float*)(tag1 + HID);                           // 28*8192 f32
  float* xp_dec = xp_enc + VOC * 4 * HID;

  // Clear tags (tag 0 never matches an expected epoch >= 1)
  hipMemsetAsync(ws + 4096, 0, 2 * HID * sizeof(unsigned long long), stream);
  k_xproj<<<NBLK, 256, 0, stream>>>(enc_emb, enc_Wih, enc_bih, enc_bhh, xp_enc);
  k_xproj<<<NBLK, 256, 0, stream>>>(dec_emb, dec_Wih, dec_bih, dec_bhh, xp_dec);

  MainArgs a;
  a.enc_Whh = enc_Whh; a.dec_Whh = dec_Whh;
  a.x = x; a.target = target; a.eps = eps;
  a.mu_W = mu_W; a.mu_b = mu_b; a.lv_W = lv_W; a.lv_b = lv_b;
  a.xp_enc = xp_enc; a.xp_dec = xp_dec;
  a.tag0 = tag0; a.tag1 = tag1;
  a.out_res = out;
  a.out_dec = out + TLEN;
  a.out_mu  = out + TLEN + (size_t)TLEN * HID;
  a.out_lv  = out + TLEN + (size_t)TLEN * HID + HID;

  void* kargs[] = {(void*)&a};
  hipLaunchCooperativeKernel((void*)k_main, dim3(NBLK), dim3(NTHR), kargs, 0, stream);

  k_argmax<<<TLEN, 256, 0, stream>>>(out + TLEN, out);
}

// Round 4
// 2799.481 us; speedup vs baseline: 2.3121x; 1.1691x over previous
//
#include <hip/hip_runtime.h>
#include <math.h>

#define HID 2048
#define VOC 28
#define TLEN 512
#define NBLK 256
#define NTHR 512

#define ATOM_ST64(p, v) __hip_atomic_store((unsigned long long*)(p), (v), __ATOMIC_RELAXED, __HIP_MEMORY_SCOPE_AGENT)
#define ATOM_LD64(p)    __hip_atomic_load((const unsigned long long*)(p), __ATOMIC_RELAXED, __HIP_MEMORY_SCOPE_AGENT)

// ---------------------------------------------------------------------------
// K1 (merged enc+dec): xp[v][row] = sum_k emb[v][k]*Wih[row][k] + bih + bhh
// blocks 0..255 -> encoder, 256..511 -> decoder
// ---------------------------------------------------------------------------
__global__ __launch_bounds__(256) void k_xproj(
    const float* __restrict__ embE, const float* __restrict__ WihE,
    const float* __restrict__ bihE, const float* __restrict__ bhhE,
    float* __restrict__ xpE,
    const float* __restrict__ embD, const float* __restrict__ WihD,
    const float* __restrict__ bihD, const float* __restrict__ bhhD,
    float* __restrict__ xpD)
{
  const float *emb, *Wih, *bih, *bhh;
  float* xp;
  int slab;
  if (blockIdx.x < NBLK) {
    emb = embE; Wih = WihE; bih = bihE; bhh = bhhE; xp = xpE; slab = blockIdx.x;
  } else {
    emb = embD; Wih = WihD; bih = bihD; bhh = bhhD; xp = xpD; slab = blockIdx.x - NBLK;
  }
  const int t = threadIdx.x;
  const int v = t & 31;             // vocab lane (>=28 inactive)
  const int sub = t >> 5;           // 8 column groups of 32 (per 256-chunk)
  const int w = t >> 6;             // wave id (4)
  __shared__ float embl[VOC][257];  // +1 pad: conflict-free row access
  __shared__ float red[4][32][33];  // +1 pad
  float acc[32];
#pragma unroll
  for (int r = 0; r < 32; ++r) acc[r] = 0.f;
  const int vv = (v < VOC) ? v : 0;
  for (int c = 0; c < 8; ++c) {
    __syncthreads();
    for (int e = t; e < VOC * 256; e += 256) {
      int ev = e >> 8, ek = e & 255;
      embl[ev][ek] = emb[ev * HID + c * 256 + ek];
    }
    __syncthreads();
    float el[32];
#pragma unroll
    for (int i = 0; i < 32; ++i) el[i] = embl[vv][sub * 32 + i];
    for (int r = 0; r < 32; ++r) {
      const float4* wr = (const float4*)(Wih + (size_t)(slab * 32 + r) * HID + c * 256 + sub * 32);
      float a = acc[r];
#pragma unroll
      for (int q = 0; q < 8; ++q) {
        float4 wv = wr[q];
        a = fmaf(el[q * 4 + 0], wv.x, a);
        a = fmaf(el[q * 4 + 1], wv.y, a);
        a = fmaf(el[q * 4 + 2], wv.z, a);
        a = fmaf(el[q * 4 + 3], wv.w, a);
      }
      acc[r] = a;
    }
  }
#pragma unroll
  for (int r = 0; r < 32; ++r) acc[r] += __shfl_xor(acc[r], 32);
  if ((t & 32) == 0) {
#pragma unroll
    for (int r = 0; r < 32; ++r) red[w][v][r] = acc[r];
  }
  __syncthreads();
  for (int p = t; p < VOC * 32; p += 256) {
    int pv = p >> 5, pr = p & 31;
    float s = red[0][pv][pr] + red[1][pv][pr] + red[2][pv][pr] + red[3][pv][pr];
    int row = slab * 32 + pr;
    xp[(size_t)pv * (4 * HID) + row] = s + bih[row] + bhh[row];
  }
}

// ---------------------------------------------------------------------------
// Persistent LSTM — tagged dataflow (payload carries discovery), now with:
//  * PAGE-SPREAD layout: producer p owns a private 4 KB page; both parity
//    slots (8 tagged 8B words each) live in it. The polled set stripes over
//    ~all LLC channels instead of 128 consecutive lines -> the per-channel
//    request serialization divisor grows.
//  * PACED polls: each thread EMA-tracks the detect->detect period via
//    s_memrealtime (100 MHz) and sleeps until prev + 5/8*P before polling.
//    Fixed point of the feedback is P* = (8/3)*discovery-latency, so pacing
//    cannot trap the period above ~2.7x the natural floor; a misprediction
//    merely degrades to plain polling.
// Protocol (unchanged, verified R1/R3): word = (epoch<<32 | f32). 2-slot
// parity rotation is race-free by induction; launch-time memset clears
// stale tags so epochs never alias across bench iterations.
// ---------------------------------------------------------------------------
struct MainArgs {
  const float* enc_Whh;
  const float* dec_Whh;
  const int* x;
  const int* target;
  const float* eps;
  const float* mu_W; const float* mu_b;
  const float* lv_W; const float* lv_b;
  const float* xp_enc; const float* xp_dec;
  unsigned long long* tags;       // 256 pages x 4 KB (page p = producer p)
  float* out_res; float* out_dec; float* out_mu; float* out_lv;
};

__device__ __forceinline__ unsigned long long pack_he(float h, unsigned e) {
  return ((unsigned long long)e << 32) | (unsigned long long)__float_as_uint(h);
}

// linear h index -> padded float index: hpad[ck][q][e] with 9-float4 rows
__device__ __forceinline__ int hp_idx(int i) {
  return ((i >> 5) * 36) + (((i >> 2) & 7) << 2) + (i & 3);
}

// word index of h element w in parity slot sl (page (w>>3), word (w&7))
__device__ __forceinline__ int wi(int w, int sl) {
  return ((w >> 3) << 9) + (sl << 3) + (w & 7);
}

// Spin-gather the full h vector for `epoch` into hpad (4 elems per thread).
// Payload-carrying poll: the load that discovers the tag IS the data load.
__device__ __forceinline__ void gather_h(const unsigned long long* __restrict__ tags,
                                         int sl, unsigned epoch, float* hpad, int t) {
  const int i0 = wi(t, sl);        // +512 in h-index == +32768 in word-index
  unsigned long long w0 = ATOM_LD64(tags + i0);
  unsigned long long w1 = ATOM_LD64(tags + i0 + 32768);
  unsigned long long w2 = ATOM_LD64(tags + i0 + 65536);
  unsigned long long w3 = ATOM_LD64(tags + i0 + 98304);
  while ((unsigned)(w0 >> 32) != epoch || (unsigned)(w1 >> 32) != epoch ||
         (unsigned)(w2 >> 32) != epoch || (unsigned)(w3 >> 32) != epoch) {
    __builtin_amdgcn_s_sleep(1);
    if ((unsigned)(w0 >> 32) != epoch) w0 = ATOM_LD64(tags + i0);
    if ((unsigned)(w1 >> 32) != epoch) w1 = ATOM_LD64(tags + i0 + 32768);
    if ((unsigned)(w2 >> 32) != epoch) w2 = ATOM_LD64(tags + i0 + 65536);
    if ((unsigned)(w3 >> 32) != epoch) w3 = ATOM_LD64(tags + i0 + 98304);
  }
  hpad[hp_idx(t)]        = __uint_as_float((unsigned)w0);
  hpad[hp_idx(t + 512)]  = __uint_as_float((unsigned)w1);
  hpad[hp_idx(t + 1024)] = __uint_as_float((unsigned)w2);
  hpad[hp_idx(t + 1536)] = __uint_as_float((unsigned)w3);
}

__global__ __launch_bounds__(NTHR) void k_main(MainArgs a) {
  const int b = blockIdx.x;
  const int t = threadIdx.x;
  const int base_j = b * 8;
  const int jj = t & 7;           // output element within the block's 8
  const int ck = t >> 3;          // 0..63 column chunk of 32 floats

  __shared__ __align__(16) float hpad[64 * 36];  // padded h (9216 B)
  __shared__ float wred[4 * 8 * 9];              // [gate][wave][jj] +1 pad
  __shared__ float gsum[32];
  __shared__ int toks[2 * TLEN];

  toks[t] = a.x[t];
  toks[TLEN + t] = (t == 0) ? 0 : a.target[t - 1];
  float c_reg = 0.f;                              // c0 = 0 (held by t<8)

  // weights: w4[g*8+q] = Whh row (g*HID + base_j + jj), cols ck*32+q*4 ..+3
  float4 w4[32];
#pragma unroll
  for (int g = 0; g < 4; ++g) {
    const float* wp = a.enc_Whh + ((size_t)(g * HID + base_j + jj)) * HID + ck * 32;
#pragma unroll
    for (int q = 0; q < 8; ++q) w4[g * 8 + q] = *(const float4*)(wp + q * 4);
  }

  unsigned epoch = 1;                             // h0 carries tag 1
  if (t < 8) ATOM_ST64(&a.tags[(b << 9) + 8 + t], pack_he(0.f, 1u)); // slot 1
  __syncthreads();                                // toks ready

  unsigned long long t_prev = __builtin_amdgcn_s_memrealtime();
  unsigned long long P_est = 0;                   // EMA period, 10ns ticks

  for (int phase = 0; phase < 2; ++phase) {
    const float* xp = phase ? a.xp_dec : a.xp_enc;
    const int* tk = &toks[phase * TLEN];
    for (int s = 0; s < TLEN; ++s) {
      // xp load first: latency hides under the sleep/spin
      float xpv = 0.f;
      if (t < 32) xpv = xp[(size_t)tk[s] * (4 * HID) + (t >> 3) * HID + base_j + (t & 7)];
      // ---- paced poll: sleep until prev_detect + 5/8 * P ----
      if (P_est > 40) {
        unsigned long long target = t_prev + ((P_est * 5) >> 3);
        unsigned long long now = __builtin_amdgcn_s_memrealtime();
        int guard = 0;
        while ((long long)(target - now) > 48 && guard < 48) {   // coarse: ~430ns
          __builtin_amdgcn_s_sleep(16);
          now = __builtin_amdgcn_s_memrealtime(); ++guard;
        }
        while ((long long)(target - now) > 12 && guard < 64) {   // fine: ~107ns
          __builtin_amdgcn_s_sleep(4);
          now = __builtin_amdgcn_s_memrealtime(); ++guard;
        }
      }
      gather_h(a.tags, epoch & 1, epoch, hpad, t);
      {
        unsigned long long now2 = __builtin_amdgcn_s_memrealtime();
        unsigned long long samp = now2 - t_prev;
        t_prev = now2;
        if (P_est == 0) P_est = samp;
        else if (samp < P_est * 3) P_est = ((P_est * 7) + samp) >> 3; // reject hiccups
      }
      __syncthreads();
      // 4-gate fused matvec: 8 ds_read_b128 + 128 FMA per thread
      float p0 = 0.f, p1 = 0.f, p2 = 0.f, p3 = 0.f;
      const float4* h4 = (const float4*)hpad;
#pragma unroll
      for (int q = 0; q < 8; ++q) {
        float4 hh = h4[ck * 9 + q];
        float4 wa = w4[q], wb = w4[8 + q], wc = w4[16 + q], wd = w4[24 + q];
        p0 = fmaf(wa.x, hh.x, p0); p0 = fmaf(wa.y, hh.y, p0);
        p0 = fmaf(wa.z, hh.z, p0); p0 = fmaf(wa.w, hh.w, p0);
        p1 = fmaf(wb.x, hh.x, p1); p1 = fmaf(wb.y, hh.y, p1);
        p1 = fmaf(wb.z, hh.z, p1); p1 = fmaf(wb.w, hh.w, p1);
        p2 = fmaf(wc.x, hh.x, p2); p2 = fmaf(wc.y, hh.y, p2);
        p2 = fmaf(wc.z, hh.z, p2); p2 = fmaf(wc.w, hh.w, p2);
        p3 = fmaf(wd.x, hh.x, p3); p3 = fmaf(wd.y, hh.y, p3);
        p3 = fmaf(wd.z, hh.z, p3); p3 = fmaf(wd.w, hh.w, p3);
      }
      // in-wave reduce across the 8 chunk-lanes (bits 3..5 of lane id)
      p0 += __shfl_xor(p0, 8);  p0 += __shfl_xor(p0, 16); p0 += __shfl_xor(p0, 32);
      p1 += __shfl_xor(p1, 8);  p1 += __shfl_xor(p1, 16); p1 += __shfl_xor(p1, 32);
      p2 += __shfl_xor(p2, 8);  p2 += __shfl_xor(p2, 16); p2 += __shfl_xor(p2, 32);
      p3 += __shfl_xor(p3, 8);  p3 += __shfl_xor(p3, 16); p3 += __shfl_xor(p3, 32);
      if ((t & 56) == 0) {                       // one lane per (wave, jj)
        int wv = t >> 6;
        wred[0 * 72 + wv * 9 + jj] = p0;         // banks distinct per store
        wred[1 * 72 + wv * 9 + jj] = p1;
        wred[2 * 72 + wv * 9 + jj] = p2;
        wred[3 * 72 + wv * 9 + jj] = p3;
      }
      __syncthreads();
      // final reduce + activations in wave 0 (t<32: gate t>>3, jj t&7)
      if (t < 32) {
        const float* wr = wred + (t >> 3) * 72 + (t & 7);
        float accv = 0.f;
#pragma unroll
        for (int w = 0; w < 8; ++w) accv += wr[w * 9];  // 32 lanes -> 32 banks
        float g = accv + xpv;
        bool is_g = (t >= 16) && (t < 24);
        float act = is_g ? tanhf(g) : (1.f / (1.f + expf(-g)));
        float sf = __shfl(act, (t & 7) + 8);
        float tg = __shfl(act, (t & 7) + 16);
        float so = __shfl(act, (t & 7) + 24);
        if (t < 8) {
          float si = act;
          c_reg = sf * c_reg + si * tg;
          float hn = so * tanhf(c_reg);
          ATOM_ST64(&a.tags[(b << 9) + (((epoch + 1) & 1) << 3) + t],
                    pack_he(hn, epoch + 1));
          if (phase) a.out_dec[(size_t)s * HID + base_j + t] = hn;
        }
      }
      ++epoch;
      // No barrier: next gather's hpad writes are safe (all hpad reads done
      // at the post-wred __syncthreads; the t<32 tail reads only wred).
    }
    if (phase == 0) {
      // ---- mu / logvar / z (h_enc carries tag `epoch`) ----
      gather_h(a.tags, epoch & 1, epoch, hpad, t);
      __syncthreads();
      const int r16 = t >> 5, cs32 = t & 31;    // 16 rows x 32 lanes
      const int mrow = base_j + (r16 & 7);
      const float* Wrow = (r16 < 8 ? a.mu_W : a.lv_W) + (size_t)mrow * HID + cs32 * 4;
      float acc = 0.f;
      const float4* h4 = (const float4*)hpad;
#pragma unroll
      for (int m = 0; m < 16; ++m) {
        float4 wv = *(const float4*)(Wrow + m * 128);
        int f = m * 32 + cs32;                   // float4 index in h
        float4 hh = h4[((f >> 3) * 9) + (f & 7)];
        acc = fmaf(wv.x, hh.x, acc);
        acc = fmaf(wv.y, hh.y, acc);
        acc = fmaf(wv.z, hh.z, acc);
        acc = fmaf(wv.w, hh.w, acc);
      }
      acc += __shfl_xor(acc, 1);
      acc += __shfl_xor(acc, 2);
      acc += __shfl_xor(acc, 4);
      acc += __shfl_xor(acc, 8);
      acc += __shfl_xor(acc, 16);
      if (cs32 == 0) gsum[r16] = acc + (r16 < 8 ? a.mu_b[mrow] : a.lv_b[mrow]);
      __syncthreads();
      if (t < 8) {
        float mu = gsum[t], lv = gsum[8 + t];
        a.out_mu[base_j + t] = mu;
        a.out_lv[base_j + t] = lv;
        float z = fmaf(a.eps[base_j + t], expf(0.5f * lv), mu);
        ATOM_ST64(&a.tags[(b << 9) + (((epoch + 1) & 1) << 3) + t],
                  pack_he(z, epoch + 1));
      }
      // reload weights for decoder (private; overlaps others' spin)
#pragma unroll
      for (int g = 0; g < 4; ++g) {
        const float* wp = a.dec_Whh + ((size_t)(g * HID + base_j + jj)) * HID + ck * 32;
#pragma unroll
        for (int q = 0; q < 8; ++q) w4[g * 8 + q] = *(const float4*)(wp + q * 4);
      }
      ++epoch;   // decoder gathers z at this tag
    }
  }
}

// ---------------------------------------------------------------------------
// Argmax over each dec_outs row (first-index tie semantics, like jnp.argmax)
// ---------------------------------------------------------------------------
__global__ __launch_bounds__(256) void k_argmax(const float* __restrict__ dec,
                                               float* __restrict__ res) {
  const int row = blockIdx.x;
  const int t = threadIdx.x;
  const float4* d4 = (const float4*)(dec + (size_t)row * HID);
  float bv = -INFINITY; int bi = 0;
#pragma unroll
  for (int k = 0; k < 2; ++k) {
    int p = t + k * 256;
    float4 v = d4[p];
    int i0 = p * 4;
    if (v.x > bv) { bv = v.x; bi = i0; }
    if (v.y > bv) { bv = v.y; bi = i0 + 1; }
    if (v.z > bv) { bv = v.z; bi = i0 + 2; }
    if (v.w > bv) { bv = v.w; bi = i0 + 3; }
  }
  for (int off = 1; off < 64; off <<= 1) {
    float ov = __shfl_xor(bv, off);
    int oi = __shfl_xor(bi, off);
    if (ov > bv || (ov == bv && oi < bi)) { bv = ov; bi = oi; }
  }
  __shared__ float sv[4];
  __shared__ int si[4];
  if ((t & 63) == 0) { sv[t >> 6] = bv; si[t >> 6] = bi; }
  __syncthreads();
  if (t == 0) {
    for (int ww = 1; ww < 4; ++ww)
      if (sv[ww] > bv || (sv[ww] == bv && si[ww] < bi)) { bv = sv[ww]; bi = si[ww]; }
    res[row] = (float)bi;
  }
}

// ---------------------------------------------------------------------------
extern "C" void kernel_launch(void* const* d_in, const int* in_sizes, int n_in,
                              void* d_out, int out_size, void* d_ws, size_t ws_size,
                              hipStream_t stream) {
  (void)in_sizes; (void)n_in; (void)out_size; (void)ws_size;
  const int* x        = (const int*)d_in[0];
  const int* target   = (const int*)d_in[1];
  const float* eps    = (const float*)d_in[2];
  const float* enc_emb = (const float*)d_in[3];
  const float* enc_Wih = (const float*)d_in[4];
  const float* enc_Whh = (const float*)d_in[5];
  const float* enc_bih = (const float*)d_in[6];
  const float* enc_bhh = (const float*)d_in[7];
  const float* mu_W   = (const float*)d_in[8];
  const float* mu_b   = (const float*)d_in[9];
  const float* lv_W   = (const float*)d_in[10];
  const float* lv_b   = (const float*)d_in[11];
  const float* dec_emb = (const float*)d_in[12];
  const float* dec_Wih = (const float*)d_in[13];
  const float* dec_Whh = (const float*)d_in[14];
  const float* dec_bih = (const float*)d_in[15];
  const float* dec_bhh = (const float*)d_in[16];

  float* out = (float*)d_out;
  char* ws = (char*)d_ws;
  unsigned long long* tags = (unsigned long long*)(ws + 4096);   // 1 MB (256 x 4 KB pages)
  float* xp_enc = (float*)(ws + 4096 + NBLK * 4096);             // 28*8192 f32
  float* xp_dec = xp_enc + VOC * 4 * HID;

  // Clear ALL tag pages: stale epochs from a previous bench iteration could
  // alias this run's expected epochs (they repeat 1..1026 every launch).
  hipMemsetAsync(tags, 0, NBLK * 4096, stream);
  k_xproj<<<2 * NBLK, 256, 0, stream>>>(enc_emb, enc_Wih, enc_bih, enc_bhh, xp_enc,
                                        dec_emb, dec_Wih, dec_bih, dec_bhh, xp_dec);

  MainArgs a;
  a.enc_Whh = enc_Whh; a.dec_Whh = dec_Whh;
  a.x = x; a.target = target; a.eps = eps;
  a.mu_W = mu_W; a.mu_b = mu_b; a.lv_W = lv_W; a.lv_b = lv_b;
  a.xp_enc = xp_enc; a.xp_dec = xp_dec;
  a.tags = tags;
  a.out_res = out;
  a.out_dec = out + TLEN;
  a.out_mu  = out + TLEN + (size_t)TLEN * HID;
  a.out_lv  = out + TLEN + (size_t)TLEN * HID + HID;

  // Regular (non-cooperative) launch: no grid-sync API is used — sync is via
  // agent-scope atomics. Residency is guaranteed by capacity: 256 blocks of
  // 512 thr / 96 VGPR / 15 KB LDS fit >= 2 per CU on 256 CUs, so every block
  // is resident regardless of packing order.
  k_main<<<NBLK, NTHR, 0, stream>>>(a);

  k_argmax<<<TLEN, 256, 0, stream>>>(out + TLEN, out);
}

// Round 5
// 2541.118 us; speedup vs baseline: 2.5472x; 1.1017x over previous
//
#include <hip/hip_runtime.h>
#include <math.h>

#define HID 2048
#define VOC 28
#define TLEN 512
#define NBLK 256
#define NTHR 512

#define ATOM_ST64(p, v) __hip_atomic_store((unsigned long long*)(p), (v), __ATOMIC_RELAXED, __HIP_MEMORY_SCOPE_AGENT)
#define ATOM_LD64(p)    __hip_atomic_load((const unsigned long long*)(p), __ATOMIC_RELAXED, __HIP_MEMORY_SCOPE_AGENT)

// ---------------------------------------------------------------------------
// K1 (merged enc+dec): xp[v][row] = sum_k emb[v][k]*Wih[row][k] + bih + bhh
// blocks 0..255 -> encoder, 256..511 -> decoder
// ---------------------------------------------------------------------------
__global__ __launch_bounds__(256) void k_xproj(
    const float* __restrict__ embE, const float* __restrict__ WihE,
    const float* __restrict__ bihE, const float* __restrict__ bhhE,
    float* __restrict__ xpE,
    const float* __restrict__ embD, const float* __restrict__ WihD,
    const float* __restrict__ bihD, const float* __restrict__ bhhD,
    float* __restrict__ xpD)
{
  const float *emb, *Wih, *bih, *bhh;
  float* xp;
  int slab;
  if (blockIdx.x < NBLK) {
    emb = embE; Wih = WihE; bih = bihE; bhh = bhhE; xp = xpE; slab = blockIdx.x;
  } else {
    emb = embD; Wih = WihD; bih = bihD; bhh = bhhD; xp = xpD; slab = blockIdx.x - NBLK;
  }
  const int t = threadIdx.x;
  const int v = t & 31;             // vocab lane (>=28 inactive)
  const int sub = t >> 5;           // 8 column groups of 32 (per 256-chunk)
  const int w = t >> 6;             // wave id (4)
  __shared__ float embl[VOC][257];  // +1 pad: conflict-free row access
  __shared__ float red[4][32][33];  // +1 pad
  float acc[32];
#pragma unroll
  for (int r = 0; r < 32; ++r) acc[r] = 0.f;
  const int vv = (v < VOC) ? v : 0;
  for (int c = 0; c < 8; ++c) {
    __syncthreads();
    for (int e = t; e < VOC * 256; e += 256) {
      int ev = e >> 8, ek = e & 255;
      embl[ev][ek] = emb[ev * HID + c * 256 + ek];
    }
    __syncthreads();
    float el[32];
#pragma unroll
    for (int i = 0; i < 32; ++i) el[i] = embl[vv][sub * 32 + i];
    for (int r = 0; r < 32; ++r) {
      const float4* wr = (const float4*)(Wih + (size_t)(slab * 32 + r) * HID + c * 256 + sub * 32);
      float a = acc[r];
#pragma unroll
      for (int q = 0; q < 8; ++q) {
        float4 wv = wr[q];
        a = fmaf(el[q * 4 + 0], wv.x, a);
        a = fmaf(el[q * 4 + 1], wv.y, a);
        a = fmaf(el[q * 4 + 2], wv.z, a);
        a = fmaf(el[q * 4 + 3], wv.w, a);
      }
      acc[r] = a;
    }
  }
#pragma unroll
  for (int r = 0; r < 32; ++r) acc[r] += __shfl_xor(acc[r], 32);
  if ((t & 32) == 0) {
#pragma unroll
    for (int r = 0; r < 32; ++r) red[w][v][r] = acc[r];
  }
  __syncthreads();
  for (int p = t; p < VOC * 32; p += 256) {
    int pv = p >> 5, pr = p & 31;
    float s = red[0][pv][pr] + red[1][pv][pr] + red[2][pv][pr] + red[3][pv][pr];
    int row = slab * 32 + pr;
    xp[(size_t)pv * (4 * HID) + row] = s + bih[row] + bhh[row];
  }
}

// ---------------------------------------------------------------------------
// Persistent LSTM — tagged dataflow (payload carries discovery), page-spread
// producer layout, and BLOCK-ANCHORED pacing:
//
//   The pacing clock is the barrier-exit timestamp (block-uniform by
//   construction), NOT each thread's own previous detect. Per-thread
//   anchoring froze the grid's phase spread (a late-detecting thread woke
//   late, polled late, detected late again — the max-of-2048-words tail
//   became the period). Anchoring to the shared barrier clock makes phase
//   errors decay: late words are polled EARLY relative to their lateness,
//   so producers' publishes align across the grid and the order-statistic
//   tail collapses toward single-publish visibility.
//
//   Wake at t_ref + 3/8*P_ema. Self-correcting both directions: P too big
//   -> wake early -> small measured samp -> EMA down; P too small -> extra
//   poll rounds -> larger samp -> EMA up. Fixed point = ready+discovery.
//
// Protocol (unchanged, verified R1/R3/R4): word = (epoch<<32 | f32). 2-slot
// parity rotation race-free by induction; launch-time memset clears stale
// tags so epochs never alias across bench iterations.
// ---------------------------------------------------------------------------
struct MainArgs {
  const float* enc_Whh;
  const float* dec_Whh;
  const int* x;
  const int* target;
  const float* eps;
  const float* mu_W; const float* mu_b;
  const float* lv_W; const float* lv_b;
  const float* xp_enc; const float* xp_dec;
  unsigned long long* tags;       // 256 pages x 4 KB (page p = producer p)
  float* out_res; float* out_dec; float* out_mu; float* out_lv;
};

__device__ __forceinline__ unsigned long long pack_he(float h, unsigned e) {
  return ((unsigned long long)e << 32) | (unsigned long long)__float_as_uint(h);
}

// linear h index -> padded float index: hpad[ck][q][e] with 9-float4 rows
__device__ __forceinline__ int hp_idx(int i) {
  return ((i >> 5) * 36) + (((i >> 2) & 7) << 2) + (i & 3);
}

// word index of h element w in parity slot sl (page (w>>3), word (w&7))
__device__ __forceinline__ int wi(int w, int sl) {
  return ((w >> 3) << 9) + (sl << 3) + (w & 7);
}

// Spin-gather the full h vector for `epoch` into hpad (4 elems per thread).
// Payload-carrying poll: the load that discovers the tag IS the data load.
__device__ __forceinline__ void gather_h(const unsigned long long* __restrict__ tags,
                                         int sl, unsigned epoch, float* hpad, int t) {
  const int i0 = wi(t, sl);        // +512 in h-index == +32768 in word-index
  unsigned long long w0 = ATOM_LD64(tags + i0);
  unsigned long long w1 = ATOM_LD64(tags + i0 + 32768);
  unsigned long long w2 = ATOM_LD64(tags + i0 + 65536);
  unsigned long long w3 = ATOM_LD64(tags + i0 + 98304);
  while ((unsigned)(w0 >> 32) != epoch || (unsigned)(w1 >> 32) != epoch ||
         (unsigned)(w2 >> 32) != epoch || (unsigned)(w3 >> 32) != epoch) {
    __builtin_amdgcn_s_sleep(1);
    if ((unsigned)(w0 >> 32) != epoch) w0 = ATOM_LD64(tags + i0);
    if ((unsigned)(w1 >> 32) != epoch) w1 = ATOM_LD64(tags + i0 + 32768);
    if ((unsigned)(w2 >> 32) != epoch) w2 = ATOM_LD64(tags + i0 + 65536);
    if ((unsigned)(w3 >> 32) != epoch) w3 = ATOM_LD64(tags + i0 + 98304);
  }
  hpad[hp_idx(t)]        = __uint_as_float((unsigned)w0);
  hpad[hp_idx(t + 512)]  = __uint_as_float((unsigned)w1);
  hpad[hp_idx(t + 1024)] = __uint_as_float((unsigned)w2);
  hpad[hp_idx(t + 1536)] = __uint_as_float((unsigned)w3);
}

__global__ __launch_bounds__(NTHR) void k_main(MainArgs a) {
  const int b = blockIdx.x;
  const int t = threadIdx.x;
  const int base_j = b * 8;
  const int jj = t & 7;           // output element within the block's 8
  const int ck = t >> 3;          // 0..63 column chunk of 32 floats

  __shared__ __align__(16) float hpad[64 * 36];  // padded h (9216 B)
  __shared__ float wred[4 * 8 * 9];              // [gate][wave][jj] +1 pad
  __shared__ float gsum[32];
  __shared__ int toks[2 * TLEN];

  toks[t] = a.x[t];
  toks[TLEN + t] = (t == 0) ? 0 : a.target[t - 1];
  float c_reg = 0.f;                              // c0 = 0 (held by t<8)

  // weights: w4[g*8+q] = Whh row (g*HID + base_j + jj), cols ck*32+q*4 ..+3
  float4 w4[32];
#pragma unroll
  for (int g = 0; g < 4; ++g) {
    const float* wp = a.enc_Whh + ((size_t)(g * HID + base_j + jj)) * HID + ck * 32;
#pragma unroll
    for (int q = 0; q < 8; ++q) w4[g * 8 + q] = *(const float4*)(wp + q * 4);
  }

  unsigned epoch = 1;                             // h0 carries tag 1
  if (t < 8) ATOM_ST64(&a.tags[(b << 9) + 8 + t], pack_he(0.f, 1u)); // slot 1
  __syncthreads();                                // toks ready

  // Block-uniform pacing state: anchored at barrier-exit (same value in
  // every thread up to a few cycles of barrier-release skew).
  unsigned long long t_ref = __builtin_amdgcn_s_memrealtime();
  unsigned long long P_est = 0;                   // EMA of barrier-to-barrier period (10ns ticks)

  for (int phase = 0; phase < 2; ++phase) {
    const float* xp = phase ? a.xp_dec : a.xp_enc;
    const int* tk = &toks[phase * TLEN];
    for (int s = 0; s < TLEN; ++s) {
      // xp load first: latency hides under the sleep/spin
      float xpv = 0.f;
      if (t < 32) xpv = xp[(size_t)tk[s] * (4 * HID) + (t >> 3) * HID + base_j + (t & 7)];
      // ---- block-anchored paced poll: sleep until t_ref + 3/8 * P ----
      if (P_est > 24) {
        unsigned long long target = t_ref + ((P_est * 3) >> 3);
        unsigned long long now = __builtin_amdgcn_s_memrealtime();
        int guard = 0;
        while ((long long)(target - now) > 24 && guard < 64) {   // ~21-tick quanta
          __builtin_amdgcn_s_sleep(8);
          now = __builtin_amdgcn_s_memrealtime(); ++guard;
        }
        while ((long long)(target - now) > 6 && guard < 96) {    // ~5-tick quanta
          __builtin_amdgcn_s_sleep(2);
          now = __builtin_amdgcn_s_memrealtime(); ++guard;
        }
      }
      gather_h(a.tags, epoch & 1, epoch, hpad, t);
      __syncthreads();
      // 4-gate fused matvec: 8 ds_read_b128 + 128 FMA per thread
      float p0 = 0.f, p1 = 0.f, p2 = 0.f, p3 = 0.f;
      const float4* h4 = (const float4*)hpad;
#pragma unroll
      for (int q = 0; q < 8; ++q) {
        float4 hh = h4[ck * 9 + q];
        float4 wa = w4[q], wb = w4[8 + q], wc = w4[16 + q], wd = w4[24 + q];
        p0 = fmaf(wa.x, hh.x, p0); p0 = fmaf(wa.y, hh.y, p0);
        p0 = fmaf(wa.z, hh.z, p0); p0 = fmaf(wa.w, hh.w, p0);
        p1 = fmaf(wb.x, hh.x, p1); p1 = fmaf(wb.y, hh.y, p1);
        p1 = fmaf(wb.z, hh.z, p1); p1 = fmaf(wb.w, hh.w, p1);
        p2 = fmaf(wc.x, hh.x, p2); p2 = fmaf(wc.y, hh.y, p2);
        p2 = fmaf(wc.z, hh.z, p2); p2 = fmaf(wc.w, hh.w, p2);
        p3 = fmaf(wd.x, hh.x, p3); p3 = fmaf(wd.y, hh.y, p3);
        p3 = fmaf(wd.z, hh.z, p3); p3 = fmaf(wd.w, hh.w, p3);
      }
      // in-wave reduce across the 8 chunk-lanes (bits 3..5 of lane id)
      p0 += __shfl_xor(p0, 8);  p0 += __shfl_xor(p0, 16); p0 += __shfl_xor(p0, 32);
      p1 += __shfl_xor(p1, 8);  p1 += __shfl_xor(p1, 16); p1 += __shfl_xor(p1, 32);
      p2 += __shfl_xor(p2, 8);  p2 += __shfl_xor(p2, 16); p2 += __shfl_xor(p2, 32);
      p3 += __shfl_xor(p3, 8);  p3 += __shfl_xor(p3, 16); p3 += __shfl_xor(p3, 32);
      if ((t & 56) == 0) {                       // one lane per (wave, jj)
        int wv = t >> 6;
        wred[0 * 72 + wv * 9 + jj] = p0;         // banks distinct per store
        wred[1 * 72 + wv * 9 + jj] = p1;
        wred[2 * 72 + wv * 9 + jj] = p2;
        wred[3 * 72 + wv * 9 + jj] = p3;
      }
      __syncthreads();
      // ---- block-uniform clock update (before the serial tail so every
      // thread reads the same barrier-exit instant) ----
      {
        unsigned long long now2 = __builtin_amdgcn_s_memrealtime();
        unsigned long long samp = now2 - t_ref;
        t_ref = now2;
        if (P_est == 0) P_est = samp;
        else if (samp < (P_est << 1)) P_est = ((P_est * 7) + samp) >> 3;
      }
      // final reduce + activations in wave 0 (t<32: gate t>>3, jj t&7)
      if (t < 32) {
        const float* wr = wred + (t >> 3) * 72 + (t & 7);
        float accv = 0.f;
#pragma unroll
        for (int w = 0; w < 8; ++w) accv += wr[w * 9];  // 32 lanes -> 32 banks
        float g = accv + xpv;
        bool is_g = (t >= 16) && (t < 24);
        float act = is_g ? tanhf(g) : (1.f / (1.f + expf(-g)));
        float sf = __shfl(act, (t & 7) + 8);
        float tg = __shfl(act, (t & 7) + 16);
        float so = __shfl(act, (t & 7) + 24);
        if (t < 8) {
          float si = act;
          c_reg = sf * c_reg + si * tg;
          float hn = so * tanhf(c_reg);
          ATOM_ST64(&a.tags[(b << 9) + (((epoch + 1) & 1) << 3) + t],
                    pack_he(hn, epoch + 1));
          if (phase) a.out_dec[(size_t)s * HID + base_j + t] = hn;
        }
      }
      ++epoch;
      // No barrier: next gather's hpad writes are safe (all hpad reads done
      // at the post-wred __syncthreads; the t<32 tail reads only wred).
    }
    if (phase == 0) {
      // ---- mu / logvar / z (h_enc carries tag `epoch`) ----
      gather_h(a.tags, epoch & 1, epoch, hpad, t);
      __syncthreads();
      const int r16 = t >> 5, cs32 = t & 31;    // 16 rows x 32 lanes
      const int mrow = base_j + (r16 & 7);
      const float* Wrow = (r16 < 8 ? a.mu_W : a.lv_W) + (size_t)mrow * HID + cs32 * 4;
      float acc = 0.f;
      const float4* h4 = (const float4*)hpad;
#pragma unroll
      for (int m = 0; m < 16; ++m) {
        float4 wv = *(const float4*)(Wrow + m * 128);
        int f = m * 32 + cs32;                   // float4 index in h
        float4 hh = h4[((f >> 3) * 9) + (f & 7)];
        acc = fmaf(wv.x, hh.x, acc);
        acc = fmaf(wv.y, hh.y, acc);
        acc = fmaf(wv.z, hh.z, acc);
        acc = fmaf(wv.w, hh.w, acc);
      }
      acc += __shfl_xor(acc, 1);
      acc += __shfl_xor(acc, 2);
      acc += __shfl_xor(acc, 4);
      acc += __shfl_xor(acc, 8);
      acc += __shfl_xor(acc, 16);
      if (cs32 == 0) gsum[r16] = acc + (r16 < 8 ? a.mu_b[mrow] : a.lv_b[mrow]);
      __syncthreads();
      if (t < 8) {
        float mu = gsum[t], lv = gsum[8 + t];
        a.out_mu[base_j + t] = mu;
        a.out_lv[base_j + t] = lv;
        float z = fmaf(a.eps[base_j + t], expf(0.5f * lv), mu);
        ATOM_ST64(&a.tags[(b << 9) + (((epoch + 1) & 1) << 3) + t],
                  pack_he(z, epoch + 1));
      }
      // reload weights for decoder (private; overlaps others' spin)
#pragma unroll
      for (int g = 0; g < 4; ++g) {
        const float* wp = a.dec_Whh + ((size_t)(g * HID + base_j + jj)) * HID + ck * 32;
#pragma unroll
        for (int q = 0; q < 8; ++q) w4[g * 8 + q] = *(const float4*)(wp + q * 4);
      }
      ++epoch;   // decoder gathers z at this tag
      // t_ref is stale by ~one step here; the first decoder-step wake target
      // is already in the past -> pacing gracefully degrades to an
      // immediate poll, and the EMA's 2x-reject drops the long sample.
    }
  }
}

// ---------------------------------------------------------------------------
// Argmax over each dec_outs row (first-index tie semantics, like jnp.argmax)
// ---------------------------------------------------------------------------
__global__ __launch_bounds__(256) void k_argmax(const float* __restrict__ dec,
                                               float* __restrict__ res) {
  const int row = blockIdx.x;
  const int t = threadIdx.x;
  const float4* d4 = (const float4*)(dec + (size_t)row * HID);
  float bv = -INFINITY; int bi = 0;
#pragma unroll
  for (int k = 0; k < 2; ++k) {
    int p = t + k * 256;
    float4 v = d4[p];
    int i0 = p * 4;
    if (v.x > bv) { bv = v.x; bi = i0; }
    if (v.y > bv) { bv = v.y; bi = i0 + 1; }
    if (v.z > bv) { bv = v.z; bi = i0 + 2; }
    if (v.w > bv) { bv = v.w; bi = i0 + 3; }
  }
  for (int off = 1; off < 64; off <<= 1) {
    float ov = __shfl_xor(bv, off);
    int oi = __shfl_xor(bi, off);
    if (ov > bv || (ov == bv && oi < bi)) { bv = ov; bi = oi; }
  }
  __shared__ float sv[4];
  __shared__ int si[4];
  if ((t & 63) == 0) { sv[t >> 6] = bv; si[t >> 6] = bi; }
  __syncthreads();
  if (t == 0) {
    for (int ww = 1; ww < 4; ++ww)
      if (sv[ww] > bv || (sv[ww] == bv && si[ww] < bi)) { bv = sv[ww]; bi = si[ww]; }
    res[row] = (float)bi;
  }
}

// ---------------------------------------------------------------------------
extern "C" void kernel_launch(void* const* d_in, const int* in_sizes, int n_in,
                              void* d_out, int out_size, void* d_ws, size_t ws_size,
                              hipStream_t stream) {
  (void)in_sizes; (void)n_in; (void)out_size; (void)ws_size;
  const int* x        = (const int*)d_in[0];
  const int* target   = (const int*)d_in[1];
  const float* eps    = (const float*)d_in[2];
  const float* enc_emb = (const float*)d_in[3];
  const float* enc_Wih = (const float*)d_in[4];
  const float* enc_Whh = (const float*)d_in[5];
  const float* enc_bih = (const float*)d_in[6];
  const float* enc_bhh = (const float*)d_in[7];
  const float* mu_W   = (const float*)d_in[8];
  const float* mu_b   = (const float*)d_in[9];
  const float* lv_W   = (const float*)d_in[10];
  const float* lv_b   = (const float*)d_in[11];
  const float* dec_emb = (const float*)d_in[12];
  const float* dec_Wih = (const float*)d_in[13];
  const float* dec_Whh = (const float*)d_in[14];
  const float* dec_bih = (const float*)d_in[15];
  const float* dec_bhh = (const float*)d_in[16];

  float* out = (float*)d_out;
  char* ws = (char*)d_ws;
  unsigned long long* tags = (unsigned long long*)(ws + 4096);   // 1 MB (256 x 4 KB pages)
  float* xp_enc = (float*)(ws + 4096 + NBLK * 4096);             // 28*8192 f32
  float* xp_dec = xp_enc + VOC * 4 * HID;

  // Clear ALL tag pages: stale epochs from a previous bench iteration could
  // alias this run's expected epochs (they repeat 1..1026 every launch).
  hipMemsetAsync(tags, 0, NBLK * 4096, stream);
  k_xproj<<<2 * NBLK, 256, 0, stream>>>(enc_emb, enc_Wih, enc_bih, enc_bhh, xp_enc,
                                        dec_emb, dec_Wih, dec_bih, dec_bhh, xp_dec);

  MainArgs a;
  a.enc_Whh = enc_Whh; a.dec_Whh = dec_Whh;
  a.x = x; a.target = target; a.eps = eps;
  a.mu_W = mu_W; a.mu_b = mu_b; a.lv_W = lv_W; a.lv_b = lv_b;
  a.xp_enc = xp_enc; a.xp_dec = xp_dec;
  a.tags = tags;
  a.out_res = out;
  a.out_dec = out + TLEN;
  a.out_mu  = out + TLEN + (size_t)TLEN * HID;
  a.out_lv  = out + TLEN + (size_t)TLEN * HID + HID;

  // Regular (non-cooperative) launch: no grid-sync API is used — sync is via
  // agent-scope atomics. Residency is guaranteed by capacity: 256 blocks of
  // 512 thr / 96 VGPR / 15 KB LDS fit >= 2 per CU on 256 CUs, so every block
  // is resident regardless of packing order.
  k_main<<<NBLK, NTHR, 0, stream>>>(a);

  k_argmax<<<TLEN, 256, 0, stream>>>(out + TLEN, out);
}